// Round 1
// baseline (492.511 us; speedup 1.0000x reference)
//
#include <hip/hip_runtime.h>

// ---- problem constants ----
constexpr int BB = 8, LL = 100, TT = 129, DD = 512, CH = 512, VV = 1000;

// output layout (floats, concatenated in return order)
constexpr int N_TEXT  = BB * LL * VV;          // 800000
constexpr int N_VIS   = BB * TT * 3;           // 3096
constexpr int N_IOU   = BB * 3 * TT * TT;      // 399384
constexpr int OUT_TEXT = 0;
constexpr int OUT_VIS  = OUT_TEXT + N_TEXT;    // 800000
constexpr int OUT_IOU  = OUT_VIS + N_VIS;      // 803096
constexpr int OUT_MASK = OUT_IOU + N_IOU;      // 1202480

// workspace layout (floats)
constexpr int WS_T1 = 0;                       // 800*512
constexpr int P_SLAB = BB * TT * DD;           // 528384
constexpr int WS_H  = WS_T1 + BB * LL * DD;    // 409600, size 1032*1536
constexpr int WS_P  = WS_H + BB * TT * 3 * DD; // 1994752, size 3*528384
constexpr int WS_U  = WS_P + 3 * P_SLAB;       // 3579904, size 3*528384

// ---------------- generic fp32 tiled GEMM: C = act(A@W + bias) ----------------
// A: M x K (row-major, leading dim lda), W: K x N (ldw), C: M x N (ldc)
template<bool RELU>
__global__ __launch_bounds__(256)
void gemm_bias_kernel(const float* __restrict__ A, int lda,
                      const float* __restrict__ W, int ldw,
                      const float* __restrict__ bias,
                      float* __restrict__ C, int ldc,
                      int M, int N, int K)
{
    __shared__ float As[16][64];   // transposed A tile: As[k][m]
    __shared__ float Ws[16][64];   // Ws[k][n]

    const int t  = threadIdx.x;
    const int tx = t & 15, ty = t >> 4;
    const int m0 = blockIdx.y * 64, n0 = blockIdx.x * 64;

    const int arow = t >> 2;          // 0..63
    const int ak   = (t & 3) << 2;    // 0,4,8,12
    const int wk   = t >> 4;          // 0..15
    const int wn   = (t & 15) << 2;   // 0..60

    float acc[4][4] = {};

    for (int k0 = 0; k0 < K; k0 += 16) {
        // stage A tile (64 rows x 16 k), store transposed
        {
            const int gm = m0 + arow;
            const float* ap = A + (size_t)gm * lda + k0 + ak;
            #pragma unroll
            for (int u = 0; u < 4; ++u)
                As[ak + u][arow] = (gm < M) ? ap[u] : 0.0f;
        }
        // stage W tile (16 k x 64 n)
        {
            const float* wp = W + (size_t)(k0 + wk) * ldw + n0 + wn;
            #pragma unroll
            for (int u = 0; u < 4; ++u)
                Ws[wk][wn + u] = (n0 + wn + u < N) ? wp[u] : 0.0f;
        }
        __syncthreads();

        #pragma unroll
        for (int kk = 0; kk < 16; ++kk) {
            float av[4], bv[4];
            #pragma unroll
            for (int u = 0; u < 4; ++u) {
                av[u] = As[kk][(ty << 2) + u];
                bv[u] = Ws[kk][(tx << 2) + u];
            }
            #pragma unroll
            for (int r = 0; r < 4; ++r)
                #pragma unroll
                for (int c = 0; c < 4; ++c)
                    acc[r][c] = fmaf(av[r], bv[c], acc[r][c]);
        }
        __syncthreads();
    }

    #pragma unroll
    for (int r = 0; r < 4; ++r) {
        const int gm = m0 + (ty << 2) + r;
        if (gm >= M) continue;
        #pragma unroll
        for (int c = 0; c < 4; ++c) {
            const int gn = n0 + (tx << 2) + c;
            if (gn >= N) continue;
            float v = acc[r][c] + (bias ? bias[gn] : 0.0f);
            if (RELU) v = fmaxf(v, 0.0f);
            C[(size_t)gm * ldc + gn] = v;
        }
    }
}

// ---------------- fused IOU grid kernel ----------------
// out[b,k,i,j] = sum_c relu(pS[b,i,c] + ps[b,(i+j)/2,c] + pE[b,j,c] + b3a[c]) * w3b[c,k] + b3b[k]
__global__ __launch_bounds__(256)
void iou_kernel(const float* __restrict__ P, const float* __restrict__ b3a,
                const float* __restrict__ w3b, const float* __restrict__ b3b,
                float* __restrict__ out)
{
    const int NP = BB * TT * TT;
    const int p = blockIdx.x * 4 + (threadIdx.x >> 6);
    if (p >= NP) return;
    const int lane = threadIdx.x & 63;
    const int b = p / (TT * TT);
    const int r = p - b * TT * TT;
    const int i = r / TT;
    const int j = r - i * TT;
    const int idx = (i + j) >> 1;

    const float* pS = P + (size_t)(b * TT + i) * DD;
    const float* ps = P + (size_t)P_SLAB + (size_t)(b * TT + idx) * DD;
    const float* pE = P + (size_t)2 * P_SLAB + (size_t)(b * TT + j) * DD;

    float a0 = 0.f, a1 = 0.f, a2 = 0.f;
    #pragma unroll
    for (int tt = 0; tt < 8; ++tt) {
        const int c = lane + (tt << 6);
        float v = pS[c] + ps[c] + pE[c] + b3a[c];
        v = fmaxf(v, 0.0f);
        a0 = fmaf(v, w3b[c * 3 + 0], a0);
        a1 = fmaf(v, w3b[c * 3 + 1], a1);
        a2 = fmaf(v, w3b[c * 3 + 2], a2);
    }
    #pragma unroll
    for (int off = 32; off; off >>= 1) {
        a0 += __shfl_xor(a0, off);
        a1 += __shfl_xor(a1, off);
        a2 += __shfl_xor(a2, off);
    }
    if (lane == 0) {
        const int base = (b * 3 * TT + i) * TT + j;
        out[OUT_IOU + base]               = a0 + b3b[0];
        out[OUT_IOU + base + TT * TT]     = a1 + b3b[1];
        out[OUT_IOU + base + 2 * TT * TT] = a2 + b3b[2];
    }
}

// ---------------- visual second-stage reduce ----------------
// out_vis[row, head] = sum_c U[head,row,c] * w2_head[c] + b2_head
__global__ __launch_bounds__(256)
void vis_reduce_kernel(const float* __restrict__ U,
                       const float* __restrict__ ws2, const float* __restrict__ we2,
                       const float* __restrict__ wc2,
                       const float* __restrict__ bs2, const float* __restrict__ be2,
                       const float* __restrict__ bc2,
                       float* __restrict__ out)
{
    const int NW = 3 * BB * TT;
    const int wid = blockIdx.x * 4 + (threadIdx.x >> 6);
    if (wid >= NW) return;
    const int lane = threadIdx.x & 63;
    const int head = wid / (BB * TT);
    const int row = wid - head * (BB * TT);
    const float* u = U + ((size_t)head * (BB * TT) + row) * DD;
    const float* w = head == 0 ? ws2 : (head == 1 ? we2 : wc2);
    const float bias = head == 0 ? bs2[0] : (head == 1 ? be2[0] : bc2[0]);
    float acc = 0.f;
    #pragma unroll
    for (int tt = 0; tt < 8; ++tt) {
        const int c = lane + (tt << 6);
        acc = fmaf(u[c], w[c], acc);
    }
    #pragma unroll
    for (int off = 32; off; off >>= 1) acc += __shfl_xor(acc, off);
    if (lane == 0) out[OUT_VIS + row * 3 + head] = acc + bias;
}

// ---------------- iou mask map ----------------
__global__ void mask_kernel(float* __restrict__ out)
{
    const int e = blockIdx.x * blockDim.x + threadIdx.x;
    if (e >= TT * TT) return;
    const int i = e / TT, j = e - i * TT;
    const int d = j - i;
    bool v = false;
    if (i < 128 && d >= 1 && d <= 16) v = true;
    if (!v && (i & 1) == 0 && i <= 110 && d >= 18 && d <= 32 && (d & 1) == 0) v = true;
    if (!v && (i & 3) == 0 && i <= 92  && d >= 36 && d <= 64 && (d & 3) == 0) v = true;
    if (!v && (i & 7) == 0 && i <= 56  && d >= 72 && (d & 7) == 0) v = true;
    out[OUT_MASK + e] = v ? 1.0f : 0.0f;
}

extern "C" void kernel_launch(void* const* d_in, const int* in_sizes, int n_in,
                              void* d_out, int out_size, void* d_ws, size_t ws_size,
                              hipStream_t stream)
{
    const float* text = (const float*)d_in[0];
    const float* obj  = (const float*)d_in[1];
    const float* w_t1 = (const float*)d_in[2];
    const float* b_t1 = (const float*)d_in[3];
    const float* w_t2 = (const float*)d_in[4];
    const float* b_t2 = (const float*)d_in[5];
    const float* w2   = (const float*)d_in[6];
    const float* b2   = (const float*)d_in[7];
    const float* w3a  = (const float*)d_in[8];
    const float* b3a  = (const float*)d_in[9];
    const float* w3b  = (const float*)d_in[10];
    const float* b3b  = (const float*)d_in[11];
    const float* w_s1 = (const float*)d_in[12];
    const float* b_s1 = (const float*)d_in[13];
    const float* w_s2 = (const float*)d_in[14];
    const float* b_s2 = (const float*)d_in[15];
    const float* w_e1 = (const float*)d_in[16];
    const float* b_e1 = (const float*)d_in[17];
    const float* w_e2 = (const float*)d_in[18];
    const float* b_e2 = (const float*)d_in[19];
    const float* w_c1 = (const float*)d_in[20];
    const float* b_c1 = (const float*)d_in[21];
    const float* w_c2 = (const float*)d_in[22];
    const float* b_c2 = (const float*)d_in[23];

    float* out = (float*)d_out;
    float* ws  = (float*)d_ws;
    float* T1  = ws + WS_T1;
    float* H   = ws + WS_H;
    float* P   = ws + WS_P;
    float* U   = ws + WS_U;

    dim3 blk(256);

    // 1) T1 = relu(text @ w_t1 + b_t1)           (800 x 512)
    gemm_bias_kernel<true><<<dim3(8, 13), blk, 0, stream>>>(
        text, DD, w_t1, CH, b_t1, T1, CH, BB * LL, CH, DD);
    // 2) logits_text = T1 @ w_t2 + b_t2          (800 x 1000)
    gemm_bias_kernel<false><<<dim3(16, 13), blk, 0, stream>>>(
        T1, CH, w_t2, VV, b_t2, out + OUT_TEXT, VV, BB * LL, VV, CH);
    // 3) H = relu(obj @ w2 + b2)                 (1032 x 1536)
    gemm_bias_kernel<true><<<dim3(24, 17), blk, 0, stream>>>(
        obj, DD, w2, 3 * DD, b2, H, 3 * DD, BB * TT, 3 * DD, DD);
    // 4-6) P parts: z=0 -> pS (hs), z=1 -> ps (hc), z=2 -> pE (he)
    for (int z = 0; z < 3; ++z)
        gemm_bias_kernel<false><<<dim3(8, 17), blk, 0, stream>>>(
            H + z * DD, 3 * DD, w3a + z * DD * DD, DD, nullptr,
            P + z * P_SLAB, DD, BB * TT, DD, DD);
    // 7-9) visual stage-1: head0=s(hs col 0), head1=e(he col 1024), head2=c(hc col 512)
    {
        const int colofs[3] = {0, 2 * DD, DD};
        const float* w1s[3] = {w_s1, w_e1, w_c1};
        const float* b1s[3] = {b_s1, b_e1, b_c1};
        for (int h = 0; h < 3; ++h)
            gemm_bias_kernel<true><<<dim3(8, 17), blk, 0, stream>>>(
                H + colofs[h], 3 * DD, w1s[h], CH, b1s[h],
                U + h * P_SLAB, CH, BB * TT, CH, DD);
    }
    // 10) visual stage-2 reduce
    vis_reduce_kernel<<<dim3((3 * BB * TT) / 4), blk, 0, stream>>>(
        U, w_s2, w_e2, w_c2, b_s2, b_e2, b_c2, out);
    // 11) fused iou grid
    iou_kernel<<<dim3((BB * TT * TT + 3) / 4), blk, 0, stream>>>(
        P, b3a, w3b, b3b, out);
    // 12) mask map
    mask_kernel<<<dim3((TT * TT + 255) / 256), blk, 0, stream>>>(out);
}

// Round 2
// 151.263 us; speedup vs baseline: 3.2560x; 3.2560x over previous
//
#include <hip/hip_runtime.h>
#include <hip/hip_bf16.h>

typedef unsigned short ushort_t;
typedef __attribute__((ext_vector_type(8))) short bf16x8;
typedef __attribute__((ext_vector_type(4))) float f32x4;

// ---- problem constants ----
constexpr int BB = 8, LL = 100, TT = 129, DD = 512, CH = 512, VV = 1000;
constexpr int M_TXT = BB * LL;          // 800
constexpr int M_OBJ = BB * TT;          // 1032
constexpr int P_SLAB = M_OBJ * DD;      // 528384

// output layout (floats)
constexpr int OUT_TEXT = 0;
constexpr int OUT_VIS  = M_TXT * VV;              // 800000
constexpr int OUT_IOU  = OUT_VIS + M_OBJ * 3;     // 803096
constexpr int OUT_MASK = OUT_IOU + BB * 3 * TT * TT; // 1202480

// workspace layout (bytes)
constexpr size_t WB_TEXT = 0;                       // 800*512*2
constexpr size_t WB_OBJ  = WB_TEXT + 819200;        // 1032*512*2
constexpr size_t WB_WT1  = WB_OBJ  + 1056768;       // 512*512*2 (transposed)
constexpr size_t WB_WT2  = WB_WT1  + 524288;        // 1000*512*2
constexpr size_t WB_W2T  = WB_WT2  + 1024000;       // 1536*512*2
constexpr size_t WB_W3AT = WB_W2T  + 1572864;       // 512*1536*2
constexpr size_t WB_WS1T = WB_W3AT + 1572864;       // 512*512*2
constexpr size_t WB_WE1T = WB_WS1T + 524288;
constexpr size_t WB_WC1T = WB_WE1T + 524288;
constexpr size_t WB_T1   = WB_WC1T + 524288;        // 800*512*2
constexpr size_t WB_H    = WB_T1   + 819200;        // 1032*1536*2
constexpr size_t WB_P    = WB_H    + 3170304;       // 3*1032*512*4 (fp32)
constexpr size_t WB_PART = WB_P    + 6340608;       // 3*1032*8*4
// total ~18.1 MB

__device__ __forceinline__ ushort_t f2bf(float x) {
    __hip_bfloat16 h = __float2bfloat16(x);
    return *(ushort_t*)&h;
}

// ---------------- activation fp32 -> bf16 (two segments) ----------------
__global__ __launch_bounds__(256)
void conv_act_kernel(const float* __restrict__ a, ushort_t* __restrict__ da, int na4,
                     const float* __restrict__ b, ushort_t* __restrict__ db, int nb4)
{
    int gid = blockIdx.x * 256 + threadIdx.x;
    const float* src; ushort_t* dst;
    if (gid < na4) { src = a + gid * 4; dst = da + gid * 4; }
    else { gid -= na4; if (gid >= nb4) return; src = b + gid * 4; dst = db + gid * 4; }
    f32x4 v = *(const f32x4*)src;
    dst[0] = f2bf(v[0]); dst[1] = f2bf(v[1]); dst[2] = f2bf(v[2]); dst[3] = f2bf(v[3]);
}

// ---------------- weight fp32 -> bf16 transposed (batched) ----------------
struct TDesc { const float* src; ushort_t* dst; int R, C, tiles, ctiles; };
struct TArgs { TDesc t[7]; };

__global__ __launch_bounds__(256)
void conv_wt_kernel(TArgs args)
{
    __shared__ float tl[32][33];
    int bx = blockIdx.x;
    TDesc e;
    #pragma unroll
    for (int i = 0; i < 7; ++i) {
        if (bx < args.t[i].tiles) { e = args.t[i]; break; }
        bx -= args.t[i].tiles;
    }
    const int tx = threadIdx.x & 31, ty = threadIdx.x >> 5;  // 32 x 8
    const int rt = bx / e.ctiles, ct = bx - rt * e.ctiles;
    #pragma unroll
    for (int i = 0; i < 4; ++i) {
        const int r = rt * 32 + ty + i * 8, c = ct * 32 + tx;
        tl[ty + i * 8][tx] = (r < e.R && c < e.C) ? e.src[(size_t)r * e.C + c] : 0.0f;
    }
    __syncthreads();
    #pragma unroll
    for (int i = 0; i < 4; ++i) {
        const int dr = ct * 32 + ty + i * 8, dc = rt * 32 + tx;
        if (dr < e.C && dc < e.R)
            e.dst[(size_t)dr * e.R + dc] = f2bf(tl[tx][ty + i * 8]);
    }
}

// ---------------- bf16 MFMA GEMM (m97 structure, 128x128 tile, BK=32) ----------------
struct GemmDesc {
    const ushort_t* A; int lda;
    const ushort_t* Bt; int ldb;     // B transposed: [N][K]
    const float* bias;
    void* C; int ldc;
    int M, N, K;
    int mode;                        // 0 = f32 out (+bias); 1 = bf16 relu (+bias); 2 = vis partial
    const float* w2head;             // mode 2
    float* partial;                  // mode 2: [M][8]
};
struct GemmArgs { GemmDesc d[6]; };

__global__ __launch_bounds__(256)
void gemm_mfma(GemmArgs args)
{
    const GemmDesc g = args.d[blockIdx.z];
    __shared__ ushort_t ldsA[2][128 * 32];
    __shared__ ushort_t ldsB[2][128 * 32];

    const int tid = threadIdx.x;
    const int w = tid >> 6, l = tid & 63;
    const int wr = w >> 1, wc = w & 1;
    const int m0 = blockIdx.y * 128, n0 = blockIdx.x * 128;

    const int srow = l >> 2;             // 0..15 within wave chunk
    const int scol = (l & 3) << 3;       // 0/8/16/24
    const int wbase = w << 4;            // wave chunk base row

    f32x4 acc[4][4];
    #pragma unroll
    for (int mi = 0; mi < 4; ++mi)
        #pragma unroll
        for (int ni = 0; ni < 4; ++ni)
            acc[mi][ni] = f32x4{0.f, 0.f, 0.f, 0.f};

    const int nk = g.K >> 5;

    auto stage = [&](int buf, int k0) {
        #pragma unroll
        for (int q = 0; q < 2; ++q) {
            int gm = m0 + (q << 6) + wbase + srow; if (gm >= g.M) gm = g.M - 1;
            __builtin_amdgcn_global_load_lds(
                (const __attribute__((address_space(1))) unsigned int*)(g.A + (size_t)gm * g.lda + k0 + scol),
                (__attribute__((address_space(3))) unsigned int*)&ldsA[buf][((q << 6) + wbase) * 32],
                16, 0, 0);
            int gn = n0 + (q << 6) + wbase + srow; if (gn >= g.N) gn = g.N - 1;
            __builtin_amdgcn_global_load_lds(
                (const __attribute__((address_space(1))) unsigned int*)(g.Bt + (size_t)gn * g.ldb + k0 + scol),
                (__attribute__((address_space(3))) unsigned int*)&ldsB[buf][((q << 6) + wbase) * 32],
                16, 0, 0);
        }
    };

    stage(0, 0);
    int cur = 0;
    const int fr = l & 15, kq = (l >> 4) << 3;

    for (int kt = 0; kt < nk; ++kt) {
        __syncthreads();
        if (kt + 1 < nk) stage(cur ^ 1, (kt + 1) << 5);
        bf16x8 av[4], bv[4];
        #pragma unroll
        for (int mi = 0; mi < 4; ++mi)
            av[mi] = *(const bf16x8*)&ldsA[cur][((wr << 6) + (mi << 4) + fr) * 32 + kq];
        #pragma unroll
        for (int ni = 0; ni < 4; ++ni)
            bv[ni] = *(const bf16x8*)&ldsB[cur][((wc << 6) + (ni << 4) + fr) * 32 + kq];
        #pragma unroll
        for (int mi = 0; mi < 4; ++mi)
            #pragma unroll
            for (int ni = 0; ni < 4; ++ni)
                acc[mi][ni] = __builtin_amdgcn_mfma_f32_16x16x32_bf16(av[mi], bv[ni], acc[mi][ni], 0, 0, 0);
        cur ^= 1;
    }

    // epilogue: C layout col = lane&15, row = (lane>>4)*4 + r
    const int rq = (l >> 4) << 2;
    if (g.mode == 2) {
        float s[4][4];
        #pragma unroll
        for (int mi = 0; mi < 4; ++mi)
            #pragma unroll
            for (int r = 0; r < 4; ++r) s[mi][r] = 0.f;
        #pragma unroll
        for (int ni = 0; ni < 4; ++ni) {
            const int col = n0 + (wc << 6) + (ni << 4) + fr;   // N=512 always in range
            const float bb = g.bias[col];
            const float wv = g.w2head[col];
            #pragma unroll
            for (int mi = 0; mi < 4; ++mi)
                #pragma unroll
                for (int r = 0; r < 4; ++r) {
                    float v = fmaxf(acc[mi][ni][r] + bb, 0.f);
                    s[mi][r] = fmaf(v, wv, s[mi][r]);
                }
        }
        #pragma unroll
        for (int off = 1; off < 16; off <<= 1)
            #pragma unroll
            for (int mi = 0; mi < 4; ++mi)
                #pragma unroll
                for (int r = 0; r < 4; ++r)
                    s[mi][r] += __shfl_xor(s[mi][r], off);
        if (fr == 0) {
            const int chunk = blockIdx.x * 2 + wc;             // 0..7
            #pragma unroll
            for (int mi = 0; mi < 4; ++mi)
                #pragma unroll
                for (int r = 0; r < 4; ++r) {
                    const int row = m0 + (wr << 6) + (mi << 4) + rq + r;
                    if (row < g.M) g.partial[row * 8 + chunk] = s[mi][r];
                }
        }
    } else {
        #pragma unroll
        for (int ni = 0; ni < 4; ++ni) {
            const int col = n0 + (wc << 6) + (ni << 4) + fr;
            const float bb = (g.bias && col < g.N) ? g.bias[col] : 0.f;
            #pragma unroll
            for (int mi = 0; mi < 4; ++mi)
                #pragma unroll
                for (int r = 0; r < 4; ++r) {
                    const int row = m0 + (wr << 6) + (mi << 4) + rq + r;
                    if (row < g.M && col < g.N) {
                        float v = acc[mi][ni][r] + bb;
                        if (g.mode == 1) {
                            v = fmaxf(v, 0.f);
                            ((ushort_t*)g.C)[(size_t)row * g.ldc + col] = f2bf(v);
                        } else {
                            ((float*)g.C)[(size_t)row * g.ldc + col] = v;
                        }
                    }
                }
        }
    }
}

// ---------------- visual second-stage reduce (8 partials per row) ----------------
__global__ __launch_bounds__(256)
void vis_reduce_kernel(const float* __restrict__ partial,
                       const float* __restrict__ bs2, const float* __restrict__ be2,
                       const float* __restrict__ bc2, float* __restrict__ out)
{
    const int gid = blockIdx.x * 256 + threadIdx.x;
    if (gid >= 3 * M_OBJ) return;
    const int head = gid / M_OBJ;
    const int row = gid - head * M_OBJ;
    const float* p = partial + (size_t)(head * M_OBJ + row) * 8;
    float s = 0.f;
    #pragma unroll
    for (int c = 0; c < 8; ++c) s += p[c];
    const float bias = head == 0 ? bs2[0] : (head == 1 ? be2[0] : bc2[0]);
    out[OUT_VIS + row * 3 + head] = s + bias;
}

// ---------------- fused IOU grid (32x32 tile, 2x2 points/thread) ----------------
__global__ __launch_bounds__(256)
void iou_kernel(const float* __restrict__ P, const float* __restrict__ w3b,
                const float* __restrict__ b3b, float* __restrict__ out)
{
    __shared__ __align__(16) float sP[96 * 132];   // 3 arrays x 32 rows x 132 (pad)
    __shared__ __align__(16) float sW[3 * 512];    // w3b transposed [k][c]

    const int tid = threadIdx.x;
    const int b = blockIdx.z;
    const int i0 = blockIdx.y * 32, j0 = blockIdx.x * 32;
    const int idx0 = (i0 + j0) >> 1;
    const int par = (i0 + j0) & 1;

    for (int f = tid; f < 1536; f += 256) {
        const int k = f >> 9, c = f & 511;
        sW[f] = w3b[c * 3 + k];
    }

    const float b3b0 = b3b[0], b3b1 = b3b[1], b3b2 = b3b[2];

    const int ii = tid >> 4, jj = tid & 15;
    float a00[3] = {0,0,0}, a01[3] = {0,0,0}, a10[3] = {0,0,0}, a11[3] = {0,0,0};
    const int o = ((ii + jj + par) >> 1) + 32;

    for (int c0 = 0; c0 < 512; c0 += 128) {
        __syncthreads();
        for (int f = tid; f < 3072; f += 256) {
            const int row = f >> 5;
            const int pos = (f & 31) << 2;
            const int a = row >> 5;
            const int r = row & 31;
            int rg = (a == 0) ? (i0 + r) : (a == 1) ? (idx0 + r) : (j0 + r);
            if (rg > 128) rg = 128;
            f32x4 v = *(const f32x4*)&P[(size_t)a * P_SLAB + ((size_t)(b * TT) + rg) * DD + c0 + pos];
            *(f32x4*)&sP[row * 132 + pos] = v;
        }
        __syncthreads();

        const float* rs0 = &sP[ii * 132];
        const float* rs1 = &sP[(ii + 16) * 132];
        const float* rp0 = &sP[o * 132];
        const float* rp1 = &sP[(o + 8) * 132];
        const float* rp2 = &sP[(o + 16) * 132];
        const float* re0 = &sP[(64 + jj) * 132];
        const float* re1 = &sP[(64 + jj + 16) * 132];

        #pragma unroll 4
        for (int c = 0; c < 128; c += 4) {
            const f32x4 s0 = *(const f32x4*)&rs0[c];
            const f32x4 s1 = *(const f32x4*)&rs1[c];
            const f32x4 p0 = *(const f32x4*)&rp0[c];
            const f32x4 p1 = *(const f32x4*)&rp1[c];
            const f32x4 p2 = *(const f32x4*)&rp2[c];
            const f32x4 e0 = *(const f32x4*)&re0[c];
            const f32x4 e1 = *(const f32x4*)&re1[c];
            const f32x4 w0 = *(const f32x4*)&sW[c0 + c];
            const f32x4 w1 = *(const f32x4*)&sW[512 + c0 + c];
            const f32x4 w2 = *(const f32x4*)&sW[1024 + c0 + c];
            #pragma unroll
            for (int u = 0; u < 4; ++u) {
                const float v00 = fmaxf(s0[u] + p0[u] + e0[u], 0.f);
                const float v01 = fmaxf(s0[u] + p1[u] + e1[u], 0.f);
                const float v10 = fmaxf(s1[u] + p1[u] + e0[u], 0.f);
                const float v11 = fmaxf(s1[u] + p2[u] + e1[u], 0.f);
                a00[0] = fmaf(v00, w0[u], a00[0]); a00[1] = fmaf(v00, w1[u], a00[1]); a00[2] = fmaf(v00, w2[u], a00[2]);
                a01[0] = fmaf(v01, w0[u], a01[0]); a01[1] = fmaf(v01, w1[u], a01[1]); a01[2] = fmaf(v01, w2[u], a01[2]);
                a10[0] = fmaf(v10, w0[u], a10[0]); a10[1] = fmaf(v10, w1[u], a10[1]); a10[2] = fmaf(v10, w2[u], a10[2]);
                a11[0] = fmaf(v11, w0[u], a11[0]); a11[1] = fmaf(v11, w1[u], a11[1]); a11[2] = fmaf(v11, w2[u], a11[2]);
            }
        }
    }

    const float bb[3] = {b3b0, b3b1, b3b2};
    auto emit = [&](const float* acc, int i, int j) {
        if (i <= 128 && j <= 128) {
            #pragma unroll
            for (int k = 0; k < 3; ++k)
                out[OUT_IOU + ((size_t)(b * 3 + k) * TT + i) * TT + j] = acc[k] + bb[k];
        }
    };
    emit(a00, i0 + ii, j0 + jj);
    emit(a01, i0 + ii, j0 + jj + 16);
    emit(a10, i0 + ii + 16, j0 + jj);
    emit(a11, i0 + ii + 16, j0 + jj + 16);
}

// ---------------- iou mask map ----------------
__global__ void mask_kernel(float* __restrict__ out)
{
    const int e = blockIdx.x * blockDim.x + threadIdx.x;
    if (e >= TT * TT) return;
    const int i = e / TT, j = e - i * TT;
    const int d = j - i;
    bool v = false;
    if (i < 128 && d >= 1 && d <= 16) v = true;
    if (!v && (i & 1) == 0 && i <= 110 && d >= 18 && d <= 32 && (d & 1) == 0) v = true;
    if (!v && (i & 3) == 0 && i <= 92  && d >= 36 && d <= 64 && (d & 3) == 0) v = true;
    if (!v && (i & 7) == 0 && i <= 56  && d >= 72 && (d & 7) == 0) v = true;
    out[OUT_MASK + e] = v ? 1.0f : 0.0f;
}

extern "C" void kernel_launch(void* const* d_in, const int* in_sizes, int n_in,
                              void* d_out, int out_size, void* d_ws, size_t ws_size,
                              hipStream_t stream)
{
    const float* text = (const float*)d_in[0];
    const float* obj  = (const float*)d_in[1];
    const float* w_t1 = (const float*)d_in[2];
    const float* b_t1 = (const float*)d_in[3];
    const float* w_t2 = (const float*)d_in[4];
    const float* b_t2 = (const float*)d_in[5];
    const float* w2   = (const float*)d_in[6];
    const float* b2   = (const float*)d_in[7];
    const float* w3a  = (const float*)d_in[8];
    const float* b3a  = (const float*)d_in[9];
    const float* w3b  = (const float*)d_in[10];
    const float* b3b  = (const float*)d_in[11];
    const float* w_s1 = (const float*)d_in[12];
    const float* b_s1 = (const float*)d_in[13];
    const float* w_s2 = (const float*)d_in[14];
    const float* b_s2 = (const float*)d_in[15];
    const float* w_e1 = (const float*)d_in[16];
    const float* b_e1 = (const float*)d_in[17];
    const float* w_e2 = (const float*)d_in[18];
    const float* b_e2 = (const float*)d_in[19];
    const float* w_c1 = (const float*)d_in[20];
    const float* b_c1 = (const float*)d_in[21];
    const float* w_c2 = (const float*)d_in[22];
    const float* b_c2 = (const float*)d_in[23];

    float* out = (float*)d_out;
    char* ws = (char*)d_ws;
    ushort_t* text_bf = (ushort_t*)(ws + WB_TEXT);
    ushort_t* obj_bf  = (ushort_t*)(ws + WB_OBJ);
    ushort_t* wt1     = (ushort_t*)(ws + WB_WT1);
    ushort_t* wt2     = (ushort_t*)(ws + WB_WT2);
    ushort_t* w2t     = (ushort_t*)(ws + WB_W2T);
    ushort_t* w3at    = (ushort_t*)(ws + WB_W3AT);
    ushort_t* ws1t    = (ushort_t*)(ws + WB_WS1T);
    ushort_t* we1t    = (ushort_t*)(ws + WB_WE1T);
    ushort_t* wc1t    = (ushort_t*)(ws + WB_WC1T);
    ushort_t* T1      = (ushort_t*)(ws + WB_T1);
    ushort_t* H       = (ushort_t*)(ws + WB_H);
    float*    P       = (float*)(ws + WB_P);
    float*    part    = (float*)(ws + WB_PART);

    // 1) activations -> bf16
    {
        const int na4 = (M_TXT * DD) / 4, nb4 = (M_OBJ * DD) / 4;
        conv_act_kernel<<<dim3((na4 + nb4 + 255) / 256), dim3(256), 0, stream>>>(
            text, text_bf, na4, obj, obj_bf, nb4);
    }
    // 2) weights -> bf16 transposed (batched, 3072 tiles)
    {
        TArgs ta;
        ta.t[0] = {w_t1, wt1, 512, 512, 256, 16};
        ta.t[1] = {w_t2, wt2, 512, 1000, 512, 32};
        ta.t[2] = {w2, w2t, 512, 1536, 768, 48};
        ta.t[3] = {w3a, w3at, 1536, 512, 768, 16};
        ta.t[4] = {w_s1, ws1t, 512, 512, 256, 16};
        ta.t[5] = {w_e1, we1t, 512, 512, 256, 16};
        ta.t[6] = {w_c1, wc1t, 512, 512, 256, 16};
        conv_wt_kernel<<<dim3(3072), dim3(256), 0, stream>>>(ta);
    }
    // 3) T1 = relu(text @ w_t1 + b_t1) -> bf16   (800 x 512)
    {
        GemmArgs a{};
        a.d[0] = {text_bf, DD, wt1, DD, b_t1, T1, CH, M_TXT, CH, DD, 1, nullptr, nullptr};
        gemm_mfma<<<dim3(4, 7, 1), dim3(256), 0, stream>>>(a);
    }
    // 4) logits_text = T1 @ w_t2 + b_t2 -> f32   (800 x 1000)
    {
        GemmArgs a{};
        a.d[0] = {T1, CH, wt2, CH, b_t2, out + OUT_TEXT, VV, M_TXT, VV, CH, 0, nullptr, nullptr};
        gemm_mfma<<<dim3(8, 7, 1), dim3(256), 0, stream>>>(a);
    }
    // 5) H = relu(obj @ w2 + b2) -> bf16         (1032 x 1536)
    {
        GemmArgs a{};
        a.d[0] = {obj_bf, DD, w2t, DD, b2, H, 3 * DD, M_OBJ, 3 * DD, DD, 1, nullptr, nullptr};
        gemm_mfma<<<dim3(12, 9, 1), dim3(256), 0, stream>>>(a);
    }
    // 6) batched 6x (1032 x 512 x 512): 3 P-projections (f32) + 3 visual stage-1 (partial)
    {
        GemmArgs a{};
        // pS = hs @ w3a[:D]  (+ b3a folded)
        a.d[0] = {H + 0 * DD, 3 * DD, w3at + 0 * DD, 3 * DD, b3a, P + 0 * P_SLAB, DD, M_OBJ, DD, DD, 0, nullptr, nullptr};
        // ps = hc @ w3a[D:2D]
        a.d[1] = {H + 1 * DD, 3 * DD, w3at + 1 * DD, 3 * DD, nullptr, P + 1 * P_SLAB, DD, M_OBJ, DD, DD, 0, nullptr, nullptr};
        // pE = he @ w3a[2D:]
        a.d[2] = {H + 2 * DD, 3 * DD, w3at + 2 * DD, 3 * DD, nullptr, P + 2 * P_SLAB, DD, M_OBJ, DD, DD, 0, nullptr, nullptr};
        // vis heads: 0=s(hs), 1=e(he), 2=c(hc)
        a.d[3] = {H + 0 * DD, 3 * DD, ws1t, DD, b_s1, nullptr, 0, M_OBJ, CH, DD, 2, w_s2, part + 0 * M_OBJ * 8};
        a.d[4] = {H + 2 * DD, 3 * DD, we1t, DD, b_e1, nullptr, 0, M_OBJ, CH, DD, 2, w_e2, part + 1 * M_OBJ * 8};
        a.d[5] = {H + 1 * DD, 3 * DD, wc1t, DD, b_c1, nullptr, 0, M_OBJ, CH, DD, 2, w_c2, part + 2 * M_OBJ * 8};
        gemm_mfma<<<dim3(4, 9, 6), dim3(256), 0, stream>>>(a);
    }
    // 7) visual stage-2 reduce
    vis_reduce_kernel<<<dim3((3 * M_OBJ + 255) / 256), dim3(256), 0, stream>>>(
        part, b_s2, b_e2, b_c2, out);
    // 8) fused iou grid
    iou_kernel<<<dim3(5, 5, 8), dim3(256), 0, stream>>>(P, w3b, b3b, out);
    // 9) mask map
    mask_kernel<<<dim3((TT * TT + 255) / 256), dim3(256), 0, stream>>>(out);
}

// Round 3
// 87.443 us; speedup vs baseline: 5.6324x; 1.7299x over previous
//
#include <hip/hip_runtime.h>
#include <hip/hip_bf16.h>

typedef unsigned short ushort_t;
typedef __attribute__((ext_vector_type(8))) short bf16x8;
typedef __attribute__((ext_vector_type(4))) float f32x4;

// ---- problem constants ----
constexpr int BB = 8, LL = 100, TT = 129, DD = 512, CH = 512, VV = 1000;
constexpr int M_TXT = BB * LL;          // 800
constexpr int M_OBJ = BB * TT;          // 1032
constexpr int P_SLAB = M_OBJ * DD;      // 528384
constexpr int N_IOU = BB * 3 * TT * TT; // 399384
constexpr int N_VIS = 3 * M_OBJ;        // 3096
constexpr int N_MASK = TT * TT;         // 16641

// output layout (floats)
constexpr int OUT_TEXT = 0;
constexpr int OUT_VIS  = M_TXT * VV;              // 800000
constexpr int OUT_IOU  = OUT_VIS + N_VIS;         // 803096
constexpr int OUT_MASK = OUT_IOU + N_IOU;         // 1202480

// workspace layout (bytes)
constexpr size_t WB_TEXT = 0;                       // 800*512*2
constexpr size_t WB_OBJ  = WB_TEXT + 819200;        // 1032*512*2
constexpr size_t WB_WT1  = WB_OBJ  + 1056768;       // 512*512*2 (transposed)
constexpr size_t WB_WT2  = WB_WT1  + 524288;        // 1000*512*2
constexpr size_t WB_W2T  = WB_WT2  + 1024000;       // 1536*512*2
constexpr size_t WB_W3AT = WB_W2T  + 1572864;       // 512*1536*2
constexpr size_t WB_WS1T = WB_W3AT + 1572864;       // 512*512*2
constexpr size_t WB_WE1T = WB_WS1T + 524288;
constexpr size_t WB_WC1T = WB_WE1T + 524288;
constexpr size_t WB_T1   = WB_WC1T + 524288;        // 800*512*2
constexpr size_t WB_H    = WB_T1   + 819200;        // 1032*1536*2
constexpr size_t WB_P    = WB_H    + 3170304;       // 3*1032*512*4 (fp32)
constexpr size_t WB_PART = WB_P    + 6340608;       // 3*1032*8*4
// iou partials (4 * N_IOU * 4B = 6.39 MB) alias the conv outputs (dead after
// gemm launch B): offsets 0 .. 6390144 — overlaps text/obj/wt1/wt2/w2t/w3at
// but NOT ws1t/we1t/wc1t/T1/H/P/PART.
constexpr size_t WB_IOUP = 0;

__device__ __forceinline__ ushort_t f2bf(float x) {
    __hip_bfloat16 h = __float2bfloat16(x);
    return *(ushort_t*)&h;
}

// ---------------- prep: activations -> bf16, weights -> bf16 transposed ----------------
struct TDesc { const float* src; ushort_t* dst; int R, C, tiles, ctiles; };
struct PrepArgs {
    const float* act_a; ushort_t* act_da; int na4;
    const float* act_b; ushort_t* act_db; int nb4;
    int nact_blocks;
    TDesc t[7];
};

__global__ __launch_bounds__(256)
void prep_kernel(PrepArgs pa)
{
    if ((int)blockIdx.x < pa.nact_blocks) {
        int gid = blockIdx.x * 256 + threadIdx.x;
        const float* src; ushort_t* dst;
        if (gid < pa.na4) { src = pa.act_a + gid * 4; dst = pa.act_da + gid * 4; }
        else { gid -= pa.na4; if (gid >= pa.nb4) return; src = pa.act_b + gid * 4; dst = pa.act_db + gid * 4; }
        f32x4 v = *(const f32x4*)src;
        dst[0] = f2bf(v[0]); dst[1] = f2bf(v[1]); dst[2] = f2bf(v[2]); dst[3] = f2bf(v[3]);
        return;
    }
    __shared__ float tl[32][33];
    int bx = blockIdx.x - pa.nact_blocks;
    TDesc e;
    #pragma unroll
    for (int i = 0; i < 7; ++i) {
        if (bx < pa.t[i].tiles) { e = pa.t[i]; break; }
        bx -= pa.t[i].tiles;
    }
    const int tx = threadIdx.x & 31, ty = threadIdx.x >> 5;  // 32 x 8
    const int rt = bx / e.ctiles, ct = bx - rt * e.ctiles;
    #pragma unroll
    for (int i = 0; i < 4; ++i) {
        const int r = rt * 32 + ty + i * 8, c = ct * 32 + tx;
        tl[ty + i * 8][tx] = (r < e.R && c < e.C) ? e.src[(size_t)r * e.C + c] : 0.0f;
    }
    __syncthreads();
    #pragma unroll
    for (int i = 0; i < 4; ++i) {
        const int dr = ct * 32 + ty + i * 8, dc = rt * 32 + tx;
        if (dr < e.C && dc < e.R)
            e.dst[(size_t)dr * e.R + dc] = f2bf(tl[tx][ty + i * 8]);
    }
}

// ---------------- bf16 MFMA GEMM (m97 structure), linear tile packing ----------------
struct GemmDesc {
    const ushort_t* A; int lda;
    const ushort_t* Bt; int ldb;     // B transposed: [N][K]
    const float* bias;
    void* C; int ldc;
    int M, N, K;
    int mode;                        // 0 = f32 out (+bias); 1 = bf16 relu (+bias); 2 = vis partial
    const float* w2head;             // mode 2
    float* partial;                  // mode 2: [M][8]
    int ntiles, ntx;
};
struct GemmArgs { GemmDesc d[7]; };

__global__ __launch_bounds__(256)
void gemm_mfma(GemmArgs args)
{
    int bx = blockIdx.x, zi = 0;
    while (bx >= args.d[zi].ntiles) { bx -= args.d[zi].ntiles; ++zi; }
    const GemmDesc g = args.d[zi];
    const int tyT = bx / g.ntx, txT = bx - tyT * g.ntx;
    const int m0 = tyT * 128, n0 = txT * 128;

    __shared__ ushort_t ldsA[2][128 * 32];
    __shared__ ushort_t ldsB[2][128 * 32];

    const int tid = threadIdx.x;
    const int w = tid >> 6, l = tid & 63;
    const int wr = w >> 1, wc = w & 1;

    const int srow = l >> 2;             // 0..15 within wave chunk
    const int scol = (l & 3) << 3;       // 0/8/16/24
    const int wbase = w << 4;            // wave chunk base row

    f32x4 acc[4][4];
    #pragma unroll
    for (int mi = 0; mi < 4; ++mi)
        #pragma unroll
        for (int ni = 0; ni < 4; ++ni)
            acc[mi][ni] = f32x4{0.f, 0.f, 0.f, 0.f};

    const int nk = g.K >> 5;

    auto stage = [&](int buf, int k0) {
        #pragma unroll
        for (int q = 0; q < 2; ++q) {
            int gm = m0 + (q << 6) + wbase + srow; if (gm >= g.M) gm = g.M - 1;
            __builtin_amdgcn_global_load_lds(
                (const __attribute__((address_space(1))) unsigned int*)(g.A + (size_t)gm * g.lda + k0 + scol),
                (__attribute__((address_space(3))) unsigned int*)&ldsA[buf][((q << 6) + wbase) * 32],
                16, 0, 0);
            int gn = n0 + (q << 6) + wbase + srow; if (gn >= g.N) gn = g.N - 1;
            __builtin_amdgcn_global_load_lds(
                (const __attribute__((address_space(1))) unsigned int*)(g.Bt + (size_t)gn * g.ldb + k0 + scol),
                (__attribute__((address_space(3))) unsigned int*)&ldsB[buf][((q << 6) + wbase) * 32],
                16, 0, 0);
        }
    };

    stage(0, 0);
    int cur = 0;
    const int fr = l & 15, kq = (l >> 4) << 3;

    for (int kt = 0; kt < nk; ++kt) {
        __syncthreads();
        if (kt + 1 < nk) stage(cur ^ 1, (kt + 1) << 5);
        bf16x8 av[4], bv[4];
        #pragma unroll
        for (int mi = 0; mi < 4; ++mi)
            av[mi] = *(const bf16x8*)&ldsA[cur][((wr << 6) + (mi << 4) + fr) * 32 + kq];
        #pragma unroll
        for (int ni = 0; ni < 4; ++ni)
            bv[ni] = *(const bf16x8*)&ldsB[cur][((wc << 6) + (ni << 4) + fr) * 32 + kq];
        #pragma unroll
        for (int mi = 0; mi < 4; ++mi)
            #pragma unroll
            for (int ni = 0; ni < 4; ++ni)
                acc[mi][ni] = __builtin_amdgcn_mfma_f32_16x16x32_bf16(av[mi], bv[ni], acc[mi][ni], 0, 0, 0);
        cur ^= 1;
    }

    // epilogue: C layout col = lane&15, row = (lane>>4)*4 + r
    const int rq = (l >> 4) << 2;
    if (g.mode == 2) {
        float s[4][4];
        #pragma unroll
        for (int mi = 0; mi < 4; ++mi)
            #pragma unroll
            for (int r = 0; r < 4; ++r) s[mi][r] = 0.f;
        #pragma unroll
        for (int ni = 0; ni < 4; ++ni) {
            const int col = n0 + (wc << 6) + (ni << 4) + fr;   // N=512 always in range
            const float bb = g.bias[col];
            const float wv = g.w2head[col];
            #pragma unroll
            for (int mi = 0; mi < 4; ++mi)
                #pragma unroll
                for (int r = 0; r < 4; ++r) {
                    float v = fmaxf(acc[mi][ni][r] + bb, 0.f);
                    s[mi][r] = fmaf(v, wv, s[mi][r]);
                }
        }
        #pragma unroll
        for (int off = 1; off < 16; off <<= 1)
            #pragma unroll
            for (int mi = 0; mi < 4; ++mi)
                #pragma unroll
                for (int r = 0; r < 4; ++r)
                    s[mi][r] += __shfl_xor(s[mi][r], off);
        if (fr == 0) {
            const int chunk = txT * 2 + wc;                    // 0..7
            #pragma unroll
            for (int mi = 0; mi < 4; ++mi)
                #pragma unroll
                for (int r = 0; r < 4; ++r) {
                    const int row = m0 + (wr << 6) + (mi << 4) + rq + r;
                    if (row < g.M) g.partial[row * 8 + chunk] = s[mi][r];
                }
        }
    } else {
        #pragma unroll
        for (int ni = 0; ni < 4; ++ni) {
            const int col = n0 + (wc << 6) + (ni << 4) + fr;
            const float bb = (g.bias && col < g.N) ? g.bias[col] : 0.f;
            #pragma unroll
            for (int mi = 0; mi < 4; ++mi)
                #pragma unroll
                for (int r = 0; r < 4; ++r) {
                    const int row = m0 + (wr << 6) + (mi << 4) + rq + r;
                    if (row < g.M && col < g.N) {
                        float v = acc[mi][ni][r] + bb;
                        if (g.mode == 1) {
                            v = fmaxf(v, 0.f);
                            ((ushort_t*)g.C)[(size_t)row * g.ldc + col] = f2bf(v);
                        } else {
                            ((float*)g.C)[(size_t)row * g.ldc + col] = v;
                        }
                    }
                }
        }
    }
}

// ---------------- iou partial (32x32 tile, 2x2 pts/thread, 128-c chunk) ----------------
__global__ __launch_bounds__(256)
void iou_partial_kernel(const float* __restrict__ P, const float* __restrict__ w3b,
                        float* __restrict__ iop)
{
    __shared__ __align__(16) float sP[96 * 132];   // 3 arrays x 32 rows x 132 (pad)
    __shared__ __align__(16) float sW[384];        // w3b chunk transposed [k][c]

    const int tid = threadIdx.x;
    const int b = blockIdx.z >> 2;
    const int cs = blockIdx.z & 3;
    const int c0 = cs << 7;
    const int i0 = blockIdx.y * 32, j0 = blockIdx.x * 32;
    const int idx0 = (i0 + j0) >> 1;
    const int par = (i0 + j0) & 1;

    for (int f = tid; f < 384; f += 256) {
        const int k = f >> 7, c = f & 127;
        sW[f] = w3b[(c0 + c) * 3 + k];
    }
    for (int f = tid; f < 3072; f += 256) {
        const int row = f >> 5;
        const int pos = (f & 31) << 2;
        const int a = row >> 5;
        const int r = row & 31;
        int rg = (a == 0) ? (i0 + r) : (a == 1) ? (idx0 + r) : (j0 + r);
        if (rg > 128) rg = 128;
        f32x4 v = *(const f32x4*)&P[(size_t)a * P_SLAB + ((size_t)(b * TT) + rg) * DD + c0 + pos];
        *(f32x4*)&sP[row * 132 + pos] = v;
    }
    __syncthreads();

    const int ii = tid >> 4, jj = tid & 15;
    const int o = ((ii + jj + par) >> 1) + 32;
    float a00[3] = {0,0,0}, a01[3] = {0,0,0}, a10[3] = {0,0,0}, a11[3] = {0,0,0};

    const float* rs0 = &sP[ii * 132];
    const float* rs1 = &sP[(ii + 16) * 132];
    const float* rp0 = &sP[o * 132];
    const float* rp1 = &sP[(o + 8) * 132];
    const float* rp2 = &sP[(o + 16) * 132];
    const float* re0 = &sP[(64 + jj) * 132];
    const float* re1 = &sP[(64 + jj + 16) * 132];

    #pragma unroll 4
    for (int c = 0; c < 128; c += 4) {
        const f32x4 s0 = *(const f32x4*)&rs0[c];
        const f32x4 s1 = *(const f32x4*)&rs1[c];
        const f32x4 p0 = *(const f32x4*)&rp0[c];
        const f32x4 p1 = *(const f32x4*)&rp1[c];
        const f32x4 p2 = *(const f32x4*)&rp2[c];
        const f32x4 e0 = *(const f32x4*)&re0[c];
        const f32x4 e1 = *(const f32x4*)&re1[c];
        const f32x4 w0 = *(const f32x4*)&sW[c];
        const f32x4 w1 = *(const f32x4*)&sW[128 + c];
        const f32x4 w2 = *(const f32x4*)&sW[256 + c];
        #pragma unroll
        for (int u = 0; u < 4; ++u) {
            const float v00 = fmaxf(s0[u] + p0[u] + e0[u], 0.f);
            const float v01 = fmaxf(s0[u] + p1[u] + e1[u], 0.f);
            const float v10 = fmaxf(s1[u] + p1[u] + e0[u], 0.f);
            const float v11 = fmaxf(s1[u] + p2[u] + e1[u], 0.f);
            a00[0] = fmaf(v00, w0[u], a00[0]); a00[1] = fmaf(v00, w1[u], a00[1]); a00[2] = fmaf(v00, w2[u], a00[2]);
            a01[0] = fmaf(v01, w0[u], a01[0]); a01[1] = fmaf(v01, w1[u], a01[1]); a01[2] = fmaf(v01, w2[u], a01[2]);
            a10[0] = fmaf(v10, w0[u], a10[0]); a10[1] = fmaf(v10, w1[u], a10[1]); a10[2] = fmaf(v10, w2[u], a10[2]);
            a11[0] = fmaf(v11, w0[u], a11[0]); a11[1] = fmaf(v11, w1[u], a11[1]); a11[2] = fmaf(v11, w2[u], a11[2]);
        }
    }

    float* dst = iop + (size_t)cs * N_IOU;
    auto emit = [&](const float* acc, int i, int j) {
        if (i <= 128 && j <= 128) {
            #pragma unroll
            for (int k = 0; k < 3; ++k)
                dst[((size_t)(b * 3 + k) * TT + i) * TT + j] = acc[k];
        }
    };
    emit(a00, i0 + ii, j0 + jj);
    emit(a01, i0 + ii, j0 + jj + 16);
    emit(a10, i0 + ii + 16, j0 + jj);
    emit(a11, i0 + ii + 16, j0 + jj + 16);
}

// ---------------- finalize: iou partial-sum + vis reduce + mask ----------------
__global__ __launch_bounds__(256)
void finalize_kernel(const float* __restrict__ iop, const float* __restrict__ part,
                     const float* __restrict__ b3b,
                     const float* __restrict__ bs2, const float* __restrict__ be2,
                     const float* __restrict__ bc2,
                     float* __restrict__ out)
{
    int g = blockIdx.x * 256 + threadIdx.x;
    if (g < N_IOU) {
        const int bk = g / (TT * TT);
        const int k = bk - (bk / 3) * 3;
        const float s = iop[g] + iop[N_IOU + g] + iop[2 * N_IOU + g] + iop[3 * N_IOU + g];
        out[OUT_IOU + g] = s + b3b[k];
        return;
    }
    g -= N_IOU;
    if (g < N_VIS) {
        const int head = g / M_OBJ;
        const int row = g - head * M_OBJ;
        const float* p = part + (size_t)(head * M_OBJ + row) * 8;
        float s = 0.f;
        #pragma unroll
        for (int c = 0; c < 8; ++c) s += p[c];
        const float bias = head == 0 ? bs2[0] : (head == 1 ? be2[0] : bc2[0]);
        out[OUT_VIS + row * 3 + head] = s + bias;
        return;
    }
    g -= N_VIS;
    if (g < N_MASK) {
        const int i = g / TT, j = g - i * TT;
        const int d = j - i;
        bool v = false;
        if (i < 128 && d >= 1 && d <= 16) v = true;
        if (!v && (i & 1) == 0 && i <= 110 && d >= 18 && d <= 32 && (d & 1) == 0) v = true;
        if (!v && (i & 3) == 0 && i <= 92  && d >= 36 && d <= 64 && (d & 3) == 0) v = true;
        if (!v && (i & 7) == 0 && i <= 56  && d >= 72 && (d & 7) == 0) v = true;
        out[OUT_MASK + g] = v ? 1.0f : 0.0f;
    }
}

extern "C" void kernel_launch(void* const* d_in, const int* in_sizes, int n_in,
                              void* d_out, int out_size, void* d_ws, size_t ws_size,
                              hipStream_t stream)
{
    const float* text = (const float*)d_in[0];
    const float* obj  = (const float*)d_in[1];
    const float* w_t1 = (const float*)d_in[2];
    const float* b_t1 = (const float*)d_in[3];
    const float* w_t2 = (const float*)d_in[4];
    const float* b_t2 = (const float*)d_in[5];
    const float* w2   = (const float*)d_in[6];
    const float* b2   = (const float*)d_in[7];
    const float* w3a  = (const float*)d_in[8];
    const float* b3a  = (const float*)d_in[9];
    const float* w3b  = (const float*)d_in[10];
    const float* b3b  = (const float*)d_in[11];
    const float* w_s1 = (const float*)d_in[12];
    const float* b_s1 = (const float*)d_in[13];
    const float* w_s2 = (const float*)d_in[14];
    const float* b_s2 = (const float*)d_in[15];
    const float* w_e1 = (const float*)d_in[16];
    const float* b_e1 = (const float*)d_in[17];
    const float* w_e2 = (const float*)d_in[18];
    const float* b_e2 = (const float*)d_in[19];
    const float* w_c1 = (const float*)d_in[20];
    const float* b_c1 = (const float*)d_in[21];
    const float* w_c2 = (const float*)d_in[22];
    const float* b_c2 = (const float*)d_in[23];

    float* out = (float*)d_out;
    char* ws = (char*)d_ws;
    ushort_t* text_bf = (ushort_t*)(ws + WB_TEXT);
    ushort_t* obj_bf  = (ushort_t*)(ws + WB_OBJ);
    ushort_t* wt1     = (ushort_t*)(ws + WB_WT1);
    ushort_t* wt2     = (ushort_t*)(ws + WB_WT2);
    ushort_t* w2t     = (ushort_t*)(ws + WB_W2T);
    ushort_t* w3at    = (ushort_t*)(ws + WB_W3AT);
    ushort_t* ws1t    = (ushort_t*)(ws + WB_WS1T);
    ushort_t* we1t    = (ushort_t*)(ws + WB_WE1T);
    ushort_t* wc1t    = (ushort_t*)(ws + WB_WC1T);
    ushort_t* T1      = (ushort_t*)(ws + WB_T1);
    ushort_t* H       = (ushort_t*)(ws + WB_H);
    float*    P       = (float*)(ws + WB_P);
    float*    part    = (float*)(ws + WB_PART);
    float*    iop     = (float*)(ws + WB_IOUP);

    // 1) prep: activations -> bf16 (916 blocks) + weight transposes (3072 blocks)
    {
        PrepArgs pa;
        pa.act_a = text; pa.act_da = text_bf; pa.na4 = (M_TXT * DD) / 4;
        pa.act_b = obj;  pa.act_db = obj_bf;  pa.nb4 = (M_OBJ * DD) / 4;
        pa.nact_blocks = (pa.na4 + pa.nb4 + 255) / 256;
        pa.t[0] = {w_t1, wt1, 512, 512, 256, 16};
        pa.t[1] = {w_t2, wt2, 512, 1000, 512, 32};
        pa.t[2] = {w2, w2t, 512, 1536, 768, 48};
        pa.t[3] = {w3a, w3at, 1536, 512, 768, 16};
        pa.t[4] = {w_s1, ws1t, 512, 512, 256, 16};
        pa.t[5] = {w_e1, we1t, 512, 512, 256, 16};
        pa.t[6] = {w_c1, wc1t, 512, 512, 256, 16};
        prep_kernel<<<dim3(pa.nact_blocks + 3072), dim3(256), 0, stream>>>(pa);
    }
    // 2) gemm launch A: T1 (800x512, 28 tiles) + H (1032x1536, 108 tiles)
    {
        GemmArgs a{};
        a.d[0] = {text_bf, DD, wt1, DD, b_t1, T1, CH, M_TXT, CH, DD, 1, nullptr, nullptr, 28, 4};
        a.d[1] = {obj_bf, DD, w2t, DD, b2, H, 3 * DD, M_OBJ, 3 * DD, DD, 1, nullptr, nullptr, 108, 12};
        gemm_mfma<<<dim3(136), dim3(256), 0, stream>>>(a);
    }
    // 3) gemm launch B: text2 (800x1000, 56 tiles) + 6x (1032x512, 36 tiles each)
    {
        GemmArgs a{};
        a.d[0] = {T1, CH, wt2, CH, b_t2, out + OUT_TEXT, VV, M_TXT, VV, CH, 0, nullptr, nullptr, 56, 8};
        a.d[1] = {H + 0 * DD, 3 * DD, w3at + 0 * DD, 3 * DD, b3a, P + 0 * P_SLAB, DD, M_OBJ, DD, DD, 0, nullptr, nullptr, 36, 4};
        a.d[2] = {H + 1 * DD, 3 * DD, w3at + 1 * DD, 3 * DD, nullptr, P + 1 * P_SLAB, DD, M_OBJ, DD, DD, 0, nullptr, nullptr, 36, 4};
        a.d[3] = {H + 2 * DD, 3 * DD, w3at + 2 * DD, 3 * DD, nullptr, P + 2 * P_SLAB, DD, M_OBJ, DD, DD, 0, nullptr, nullptr, 36, 4};
        a.d[4] = {H + 0 * DD, 3 * DD, ws1t, DD, b_s1, nullptr, 0, M_OBJ, CH, DD, 2, w_s2, part + 0 * M_OBJ * 8, 36, 4};
        a.d[5] = {H + 2 * DD, 3 * DD, we1t, DD, b_e1, nullptr, 0, M_OBJ, CH, DD, 2, w_e2, part + 1 * M_OBJ * 8, 36, 4};
        a.d[6] = {H + 1 * DD, 3 * DD, wc1t, DD, b_c1, nullptr, 0, M_OBJ, CH, DD, 2, w_c2, part + 2 * M_OBJ * 8, 36, 4};
        gemm_mfma<<<dim3(272), dim3(256), 0, stream>>>(a);
    }
    // 4) iou partials: 5x5 tiles x (8 b x 4 c-splits) = 800 blocks
    iou_partial_kernel<<<dim3(5, 5, 32), dim3(256), 0, stream>>>(P, w3b, iop);
    // 5) finalize: iou sum + vis reduce + mask (419121 elements)
    finalize_kernel<<<dim3((N_IOU + N_VIS + N_MASK + 255) / 256), dim3(256), 0, stream>>>(
        iop, part, b3b, b_s2, b_e2, b_c2, out);
}